// Round 6
// baseline (28.761 us; speedup 1.0000x reference)
//
#include <hip/hip_runtime.h>
#include <math.h>

#define EPSF 1e-6f
#define CCF  0.01f
#define SQRT_C 0.1f

typedef __attribute__((ext_vector_type(8))) short bf16x8;
typedef __attribute__((ext_vector_type(4))) float f32x4;

__device__ __forceinline__ float wred(float v) {
#pragma unroll
    for (int o = 32; o > 0; o >>= 1) v += __shfl_xor(v, o, 64);
    return v;
}

__device__ __forceinline__ unsigned f2bf1(float x) {
    unsigned u = __builtin_bit_cast(unsigned, x);
    return (u + 0x7FFFu + ((u >> 16) & 1u)) >> 16;   // RTNE
}
__device__ __forceinline__ uint2 pack4(float4 v) {
    uint2 r;
    r.x = f2bf1(v.x) | (f2bf1(v.y) << 16);
    r.y = f2bf1(v.z) | (f2bf1(v.w) << 16);
    return r;
}

// blocks 0-127: rel_h = exp_map(rel) -> bf16 row-major [512][256] + y2 (f32)
// blocks 128-159: transpose+convert Ws,Wo -> WT bf16, WT[mat][n][k] = W[k][n]
__global__ __launch_bounds__(256) void k_prep(const float* __restrict__ rel,
                                              const float* __restrict__ Ws,
                                              const float* __restrict__ Wo,
                                              unsigned short* __restrict__ relbf,
                                              float* __restrict__ y2,
                                              unsigned short* __restrict__ WT) {
    __shared__ float tile[64][65];
    int blk = blockIdx.x;
    int t = threadIdx.x;
    if (blk < 128) {
        int wave = t >> 6, lane = t & 63;
        int r = blk * 4 + wave;   // 0..511
        float4 v = *(const float4*)(rel + (size_t)r * 256 + lane * 4);
        float ss = v.x * v.x;
        ss = fmaf(v.y, v.y, ss);
        ss = fmaf(v.z, v.z, ss);
        ss = fmaf(v.w, v.w, ss);
        ss = wred(ss);
        float n = fmaxf(sqrtf(ss), EPSF);
        float s = tanhf(SQRT_C * n) / (SQRT_C * n);
        v.x *= s; v.y *= s; v.z *= s; v.w *= s;
        *(uint2*)(relbf + (size_t)r * 256 + lane * 4) = pack4(v);
        if (lane == 0) y2[r] = s * s * ss;
    } else {
        int blk2 = blk - 128;          // 0..31
        int mat = blk2 >> 4;           // 0: Ws, 1: Wo
        int tl = blk2 & 15;
        int k0 = (tl >> 2) * 64, n0 = (tl & 3) * 64;
        const float* __restrict__ W = mat ? Wo : Ws;
#pragma unroll 4
        for (int p = 0; p < 16; ++p) {
            int i = p * 4 + (t >> 6);
            tile[i][t & 63] = W[(size_t)(k0 + i) * 256 + n0 + (t & 63)];
        }
        __syncthreads();
#pragma unroll 4
        for (int p = 0; p < 16; ++p) {
            int n = p * 4 + (t >> 6);
            int j = t & 63;
            WT[(size_t)mat * 65536 + (size_t)(n0 + n) * 256 + k0 + j] = (unsigned short)f2bf1(tile[j][n]);
        }
    }
}

// Fused main: gather+log -> bf16 LDS A -> MFMA GEMM1 -> mobius -> MFMA GEMM2
// -> closed-form distance epilogue. 256 blocks x 1024 threads (16 waves).
__global__ __launch_bounds__(1024) void k_main(const float* __restrict__ E,
                                               const int* __restrict__ trip,
                                               const unsigned short* __restrict__ WT,
                                               const unsigned short* __restrict__ relbf,
                                               const float* __restrict__ y2,
                                               const float* __restrict__ rbias,
                                               float* __restrict__ out) {
    __shared__ unsigned short Abf[2][16][256];  // [0]=s rows, [1]=o rows; rows 4-15 garbage (ignored D rows)
    __shared__ float T[8][256];                 // tangent rows: 0-3 s, 4-7 o
    __shared__ unsigned short Qbf[16][256];     // query bf16 rows 0-3; rest garbage
    __shared__ float q2s[4];

    int b0 = blockIdx.x * 4;
    int t = threadIdx.x;
    int w = t >> 6, lane = t & 63;
    int row16 = lane & 15, g = lane >> 4;

    // ---- Phase A: gather + log_map (waves 0-7), write bf16 A rows swizzled ----
    if (w < 8) {
        int b = b0 + (w & 3);
        int col = (w >> 2) ? 2 : 0;
        int idx = trip[b * 3 + col];
        idx = max(0, min(idx, 19999));
        float4 v = *(const float4*)(E + (size_t)idx * 256 + lane * 4);
        float ss = v.x * v.x;
        ss = fmaf(v.y, v.y, ss);
        ss = fmaf(v.z, v.z, ss);
        ss = fmaf(v.w, v.w, ss);
        ss = wred(ss);
        float n = fmaxf(sqrtf(ss), EPSF);
        float arg = fminf(SQRT_C * n, 1.f - 1e-5f);
        float s = atanhf(arg) / (SQRT_C * n);
        v.x *= s; v.y *= s; v.z *= s; v.w *= s;
        int r = w & 3;
        char* base = (char*)&Abf[w >> 2][0][0];
        *(uint2*)(base + r * 512 + ((lane * 8) ^ (r << 4))) = pack4(v);
    }
    __syncthreads();

    // ---- Phase B: GEMM1 (tangent = A @ W). wave w: mat=w>>3, cols (w&7)*32 .. +31 ----
    {
        int mat = w >> 3;
        int nb = (w & 7) * 32;
        const char* Abase = (const char*)&Abf[mat][0][0];
        bf16x8 af[8];
#pragma unroll
        for (int kt = 0; kt < 8; ++kt)
            af[kt] = *(const bf16x8*)(Abase + row16 * 512 + ((kt * 64 + g * 16) ^ (row16 << 4)));
        f32x4 acc0 = {0.f, 0.f, 0.f, 0.f};
        f32x4 acc1 = {0.f, 0.f, 0.f, 0.f};
        const unsigned short* Wb = WT + (size_t)mat * 65536;
#pragma unroll
        for (int kt = 0; kt < 8; ++kt) {
            bf16x8 bf0 = *(const bf16x8*)(Wb + (size_t)(nb + row16) * 256 + kt * 32 + g * 8);
            bf16x8 bf1 = *(const bf16x8*)(Wb + (size_t)(nb + 16 + row16) * 256 + kt * 32 + g * 8);
            acc0 = __builtin_amdgcn_mfma_f32_16x16x32_bf16(af[kt], bf0, acc0, 0, 0, 0);
            acc1 = __builtin_amdgcn_mfma_f32_16x16x32_bf16(af[kt], bf1, acc1, 0, 0, 0);
        }
        // D layout: col=lane&15, row=(lane>>4)*4+i  -> real rows 0-3 live in lanes 0-15
        if (lane < 16) {
#pragma unroll
            for (int i = 0; i < 4; ++i) {
                T[mat * 4 + i][nb + lane]      = acc0[i];
                T[mat * 4 + i][nb + 16 + lane] = acc1[i];
            }
        }
    }
    __syncthreads();

    // ---- Phase C: exp_map + mobius_add(-s_h, o_h) (waves 0-3, f32) ----
    if (w < 4) {
        float4 sv = *(const float4*)&T[w][lane * 4];
        float4 ov = *(const float4*)&T[4 + w][lane * 4];
        float sss = sv.x * sv.x, sso = ov.x * ov.x, sdot = sv.x * ov.x;
        sss = fmaf(sv.y, sv.y, sss); sso = fmaf(ov.y, ov.y, sso); sdot = fmaf(sv.y, ov.y, sdot);
        sss = fmaf(sv.z, sv.z, sss); sso = fmaf(ov.z, ov.z, sso); sdot = fmaf(sv.z, ov.z, sdot);
        sss = fmaf(sv.w, sv.w, sss); sso = fmaf(ov.w, ov.w, sso); sdot = fmaf(sv.w, ov.w, sdot);
        sss = wred(sss); sso = wred(sso); sdot = wred(sdot);
        float ns = fmaxf(sqrtf(sss), EPSF);
        float no = fmaxf(sqrtf(sso), EPSF);
        float scs = tanhf(SQRT_C * ns) / (SQRT_C * ns);
        float sco = tanhf(SQRT_C * no) / (SQRT_C * no);
        float x2 = scs * scs * sss;
        float yy2 = sco * sco * sso;
        float xy = -scs * sco * sdot;
        float a1 = 1.f + 2.f * CCF * xy + CCF * yy2;
        float b1 = 1.f - CCF * x2;
        float den = 1.f + 2.f * CCF * xy + CCF * CCF * x2 * yy2 + EPSF;
        float rden = 1.f / den;
        float4 qv;
        qv.x = (a1 * (-scs * sv.x) + b1 * (sco * ov.x)) * rden;
        qv.y = (a1 * (-scs * sv.y) + b1 * (sco * ov.y)) * rden;
        qv.z = (a1 * (-scs * sv.z) + b1 * (sco * ov.z)) * rden;
        qv.w = (a1 * (-scs * sv.w) + b1 * (sco * ov.w)) * rden;
        float qq = qv.x * qv.x;
        qq = fmaf(qv.y, qv.y, qq);
        qq = fmaf(qv.z, qv.z, qq);
        qq = fmaf(qv.w, qv.w, qq);
        qq = wred(qq);
        char* qb = (char*)&Qbf[0][0];
        *(uint2*)(qb + w * 512 + ((lane * 8) ^ (w << 4))) = pack4(qv);
        if (lane == 0) q2s[w] = qq;
    }
    __syncthreads();

    // ---- Phase D: GEMM2 (query . rel_h) + closed-form distance epilogue ----
    {
        int nb = w * 32;
        const char* Qbase = (const char*)&Qbf[0][0];
        bf16x8 qf[8];
#pragma unroll
        for (int kt = 0; kt < 8; ++kt)
            qf[kt] = *(const bf16x8*)(Qbase + row16 * 512 + ((kt * 64 + g * 16) ^ (row16 << 4)));
        f32x4 acc0 = {0.f, 0.f, 0.f, 0.f};
        f32x4 acc1 = {0.f, 0.f, 0.f, 0.f};
#pragma unroll
        for (int kt = 0; kt < 8; ++kt) {
            bf16x8 b0v = *(const bf16x8*)(relbf + (size_t)(nb + row16) * 256 + kt * 32 + g * 8);
            bf16x8 b1v = *(const bf16x8*)(relbf + (size_t)(nb + 16 + row16) * 256 + kt * 32 + g * 8);
            acc0 = __builtin_amdgcn_mfma_f32_16x16x32_bf16(qf[kt], b0v, acc0, 0, 0, 0);
            acc1 = __builtin_amdgcn_mfma_f32_16x16x32_bf16(qf[kt], b1v, acc1, 0, 0, 0);
        }
        if (lane < 16) {
#pragma unroll
            for (int tt = 0; tt < 2; ++tt) {
                int r = nb + tt * 16 + lane;
                f32x4 a = tt ? acc1 : acc0;
                float y2r = y2[r];
                float rb = rbias[r];
#pragma unroll
                for (int m = 0; m < 4; ++m) {
                    float xy = -a[m];       // dot(-query, rel_h)
                    float x2 = q2s[m];
                    float a1 = 1.f + 2.f * CCF * xy + CCF * y2r;
                    float b1 = 1.f - CCF * x2;
                    float den = 1.f + 2.f * CCF * xy + CCF * CCF * x2 * y2r + EPSF;
                    float num2 = a1 * a1 * x2 + 2.f * a1 * b1 * xy + b1 * b1 * y2r;
                    out[(size_t)(b0 + m) * 512 + r] = -(num2 / (den * den)) + rb;
                }
            }
        }
    }
}

extern "C" void kernel_launch(void* const* d_in, const int* in_sizes, int n_in,
                              void* d_out, int out_size, void* d_ws, size_t ws_size,
                              hipStream_t stream) {
    const float* E = (const float*)d_in[0];          // 20000 x 256
    const float* rel = (const float*)d_in[1];        // 512 x 256
    const int* trip = (const int*)d_in[2];           // 1024 x 3 (int32)
    const float* Ws = (const float*)d_in[3];         // 256 x 256
    const float* Wo = (const float*)d_in[4];         // 256 x 256
    const float* rbias = (const float*)d_in[5];      // 512
    float* out = (float*)d_out;                      // 1024 x 512

    char* wsb = (char*)d_ws;
    unsigned short* relbf = (unsigned short*)wsb;                    // 512*256*2 = 262144 B
    float* y2             = (float*)(wsb + 262144);                  // 2048 B
    unsigned short* WT    = (unsigned short*)(wsb + 262144 + 2048);  // 2*256*256*2 = 262144 B

    k_prep<<<160, 256, 0, stream>>>(rel, Ws, Wo, relbf, y2, WT);
    k_main<<<256, 1024, 0, stream>>>(E, trip, WT, relbf, y2, rbias, out);
}